// Round 4
// baseline (568.850 us; speedup 1.0000x reference)
//
#include <hip/hip_runtime.h>

#define DT (1.0f/60.0f)
#define G_ACC 9.81f
#define RHO 1.225f
#define CD_ 0.47f
#define NU 0.001f

__device__ __forceinline__ float softplus_f(float x) {
    return log1pf(expf(-fabsf(x))) + fmaxf(x, 0.0f);
}

// readlane: lane index is wave-uniform (q*16+jj, q uniform per wave)
#define RL(v, l) __int_as_float(__builtin_amdgcn_readlane(__float_as_int(v), (l)))
// force a block-uniform float into an SGPR
#define SLANE(x) __int_as_float(__builtin_amdgcn_readfirstlane(__float_as_int(x)))

// DPP x-shifts within 16-lane rows (x = lane&15); bound_ctrl=1 -> 0 at edges
__device__ __forceinline__ float dpp_xm(float v) { // from x-1, 0 at x==0
    return __int_as_float(__builtin_amdgcn_update_dpp(0, __float_as_int(v), 0x111, 0xf, 0xf, true));
}
__device__ __forceinline__ float dpp_xp(float v) { // from x+1, 0 at x==15
    return __int_as_float(__builtin_amdgcn_update_dpp(0, __float_as_int(v), 0x101, 0xf, 0xf, true));
}

// grid = 2048 x 256: blocks [0,1536) fluid (ch=blk>>9, b=blk&511),
// [1536,2048) particle. 2048 blocks x 4 waves = 8192 waves = full chip
// residency iff VGPR<=64 (launch_bounds) and LDS<=~20KB (19712B).
__global__ __launch_bounds__(256, 8) void fused_kernel(
    const float* __restrict__ pos, const float* __restrict__ vel,
    const float* __restrict__ rot, const float* __restrict__ omega,
    const float* __restrict__ mass, const float* __restrict__ inertia,
    const float* __restrict__ contacts, const float* __restrict__ energy,
    const float* __restrict__ fluid, const float* __restrict__ Fext,
    const float* __restrict__ tau, const float* __restrict__ log_A,
    const float* __restrict__ log_k, const float* __restrict__ log_b,
    const float* __restrict__ conv_w, float* __restrict__ out)
{
    __shared__ float smem[4928];   // fluid: u[4352]+zcol[16]+red[4]; particle: cont[4160]+sF[768]
    const int t = threadIdx.x;

    if (blockIdx.x < 1536) {
        // ================= FLUID =================
        const int b  = blockIdx.x & 511;
        const int ch = blockIdx.x >> 9;
        const int x  = t & 15, y = t >> 4, wv = t >> 6;
        float* u   = smem;                 // col*17 + z  (17 odd -> conflict-free)
        float* red = smem + 4368;
        if (t < 16) smem[4352 + t] = 0.f;  // zero column for y-edge padding

        // weights -> SGPRs, NU pre-folded
        float W[27];
        #pragma unroll
        for (int k = 0; k < 27; ++k) W[k] = NU * SLANE(conv_w[ch*27 + k]);

        const int lb = t*17;
        const float* fb = fluid + (size_t)b*12288 + 3*t + ch;
        float base[16], acc[16];
        #pragma unroll
        for (int z = 0; z < 16; ++z) {
            float v = fb[z*768];
            base[z] = v; acc[z] = 0.f; u[lb + z] = v;
        }

        // valid-tap weight sums (already NU-scaled): k = o - mean*Sz
        const float xm = (x > 0) ? 1.f : 0.f, xp = (x < 15) ? 1.f : 0.f;
        const float mm = (y > 0) ? 1.f : 0.f, pm = (y < 15) ? 1.f : 0.f;
        float Sdz0, Sdz1, Sdz2;
        {
            float a0 = W[0]*xm + W[1] + W[2]*xp;
            float a1 = W[3]*xm + W[4] + W[5]*xp;
            float a2 = W[6]*xm + W[7] + W[8]*xp;
            Sdz0 = mm*a0 + a1 + pm*a2;
            a0 = W[ 9]*xm + W[10] + W[11]*xp;
            a1 = W[12]*xm + W[13] + W[14]*xp;
            a2 = W[15]*xm + W[16] + W[17]*xp;
            Sdz1 = mm*a0 + a1 + pm*a2;
            a0 = W[18]*xm + W[19] + W[20]*xp;
            a1 = W[21]*xm + W[22] + W[23]*xp;
            a2 = W[24]*xm + W[25] + W[26]*xp;
            Sdz2 = mm*a0 + a1 + pm*a2;
        }
        const float SzLo = Sdz1 + Sdz2, SzHi = Sdz0 + Sdz1, SzMid = Sdz0 + Sdz1 + Sdz2;
        const int cm = (y > 0)  ? lb - 272 : 4352;   // zero column at edges
        const int cp = (y < 15) ? lb + 272 : 4352;

        __syncthreads();                             // B1: planes + zero col ready
        float mean = 0.f;

        // scatter-form z-conv: value at z feeds o[z-1],o[z],o[z+1]; 3 rolling temps
        #define SEC(ca, dy) { \
            _Pragma("unroll") \
            for (int z = 0; z < 16; ++z) { \
                float c  = u[(ca) + z]; \
                float cl = dpp_xm(c), cr = dpp_xp(c); \
                o[z] += W[9+(dy)*3+1]*c + W[9+(dy)*3]*cl + W[9+(dy)*3+2]*cr; \
                if (z < 15) o[z+1] += W[(dy)*3+1]*c + W[(dy)*3]*cl + W[(dy)*3+2]*cr; \
                if (z > 0)  o[z-1] += W[18+(dy)*3+1]*c + W[18+(dy)*3]*cl + W[18+(dy)*3+2]*cr; \
            } }

        #pragma unroll
        for (int s = 0; s < 4; ++s) {
            float o[16];
            #pragma unroll
            for (int z = 0; z < 16; ++z) o[z] = 0.f;
            SEC(lb, 1);   // dy = 0
            SEC(cm, 0);   // dy = -1 (zero col at y==0)
            SEC(cp, 2);   // dy = +1

            if (s < 3) {
                const float h = (s == 2) ? DT : DT*0.5f;
                const float w = (s == 0) ? 1.f : 2.f;
                float ps = 0.f;
                #pragma unroll
                for (int z = 0; z < 16; ++z) {
                    float Sz = (z == 0) ? SzLo : ((z == 15) ? SzHi : SzMid);
                    float k = o[z] - mean * Sz;
                    acc[z] += w * k;
                    float v = base[z] + h * k;
                    o[z] = v; ps += v;
                }
                #pragma unroll
                for (int off = 32; off > 0; off >>= 1) ps += __shfl_xor(ps, off, 64);
                __syncthreads();             // WAR: all conv reads of state s done
                #pragma unroll
                for (int z = 0; z < 16; ++z) u[lb + z] = o[z];
                if ((t & 63) == 0) red[wv] = ps;
                __syncthreads();             // writes + red visible
                mean = (red[0] + red[1] + red[2] + red[3]) * (1.0f/4096.0f);
            } else {
                #pragma unroll
                for (int z = 0; z < 16; ++z) {
                    float Sz = (z == 0) ? SzLo : ((z == 15) ? SzHi : SzMid);
                    acc[z] += o[z] - mean * Sz;
                }
            }
        }
        #undef SEC

        float ps = 0.f;
        float o[16];
        #pragma unroll
        for (int z = 0; z < 16; ++z) { o[z] = base[z] + (DT/6.0f)*acc[z]; ps += o[z]; }
        #pragma unroll
        for (int off = 32; off > 0; off >>= 1) ps += __shfl_xor(ps, off, 64);
        __syncthreads();                     // WAR on red vs stage-2 mean reads
        if ((t & 63) == 0) red[wv] = ps;
        __syncthreads();
        const float mn = (red[0] + red[1] + red[2] + red[3]) * (1.0f/4096.0f);

        float* ob = out + (size_t)b*13313 + 1025 + 3*t + ch;
        #pragma unroll
        for (int z = 0; z < 16; ++z) ob[z*768] = o[z] - mn;
        return;
    }

    // ================= PARTICLE =================
    const int b = blockIdx.x - 1536;
    const int q = t >> 6;       // j-chunk / wave id
    const int i = t & 63;       // particle id
    float* cont = smem;         // [i*65 + j] : 65 odd -> 2-way (free)
    float* sF   = smem + 4160;  // [q*192 + i*3 + c]

    {   // cooperative coalesced load of contacts into LDS
        const float4* cg = (const float4*)(contacts + (size_t)b*4096);
        #pragma unroll
        for (int v = 0; v < 4; ++v) {
            float4 c4 = cg[v*256 + t];
            int fi = (v*256 + t) * 4;
            int r = fi >> 6, cc = fi & 63;
            float* p = cont + r*65 + cc;
            p[0] = c4.x; p[1] = c4.y; p[2] = c4.z; p[3] = c4.w;
        }
    }

    const size_t p3 = ((size_t)b*64 + i)*3;
    const size_t p4 = ((size_t)b*64 + i)*4;
    float bpx=pos[p3],   bpy=pos[p3+1],   bpz=pos[p3+2];
    float bvx=vel[p3],   bvy=vel[p3+1],   bvz=vel[p3+2];
    float brw=rot[p4],   brx=rot[p4+1],   bry=rot[p4+2],  brz=rot[p4+3];
    float box=omega[p3], boy=omega[p3+1], boz=omega[p3+2];
    float m  = mass[(size_t)b*64+i];
    float Ix=inertia[p3], Iy=inertia[p3+1], Iz=inertia[p3+2];
    float Fex=Fext[p3],   Fey=Fext[p3+1],   Fez=Fext[p3+2];
    float tx=tau[p3],     ty=tau[p3+1],     tz=tau[p3+2];
    float dragc = -0.5f * RHO * CD_ * softplus_f(log_A[i]);
    float kc = softplus_f(SLANE(log_k[0]));
    float bc = softplus_f(SLANE(log_b[0]));
    float invm = 1.0f / m;
    float iIx = 1.0f/fmaxf(Ix,1e-6f), iIy = 1.0f/fmaxf(Iy,1e-6f), iIz = 1.0f/fmaxf(Iz,1e-6f);

    float cpx=bpx, cpy=bpy, cpz=bpz;
    float cvx=bvx, cvy=bvy, cvz=bvz;
    float crw=brw, crx=brx, cry=bry, crz=brz;
    float cox=box, coy=boy, coz=boz;

    float apx=0,apy=0,apz=0, avx=0,avy=0,avz=0;
    float arw=0,arx=0,ary=0,arz=0, awx=0,awy=0,awz=0;
    float eacc=0.f;

    const int j0 = q << 4;
    float* ob = out + (size_t)b * 13313;
    __syncthreads();   // contacts staged

    #pragma unroll
    for (int s = 0; s < 4; ++s) {
        float Fcx=0.f, Fcy=0.f, Fcz=0.f;
        #pragma unroll
        for (int jj = 0; jj < 16; ++jj) {
            const int j = j0 + jj;
            float pjx = RL(cpx, j), pjy = RL(cpy, j), pjz = RL(cpz, j);
            float vjx = RL(cvx, j), vjy = RL(cvy, j), vjz = RL(cvz, j);
            float dx = pjx - cpx, dy = pjy - cpy, dz = pjz - cpz;
            float dist = fmaxf(sqrtf(dx*dx + dy*dy + dz*dz), 1e-6f);
            float pen  = fmaxf(1.0f - dist, 0.0f);
            float coef = kc * pen * __builtin_amdgcn_rcpf(dist);
            float cbj  = bc * cont[i*65 + j];
            Fcx += coef*dx + cbj*(vjx - cvx);
            Fcy += coef*dy + cbj*(vjy - cvy);
            Fcz += coef*dz + cbj*(vjz - cvz);
        }
        sF[q*192 + i*3+0] = Fcx;
        sF[q*192 + i*3+1] = Fcy;
        sF[q*192 + i*3+2] = Fcz;
        __syncthreads();
        Fcx = sF[i*3+0] + sF[192+i*3+0] + sF[384+i*3+0] + sF[576+i*3+0];
        Fcy = sF[i*3+1] + sF[192+i*3+1] + sF[384+i*3+1] + sF[576+i*3+1];
        Fcz = sF[i*3+2] + sF[192+i*3+2] + sF[384+i*3+2] + sF[576+i*3+2];

        float vm = fmaxf(sqrtf(cvx*cvx+cvy*cvy+cvz*cvz), 1e-6f);
        float dc = dragc * vm;
        float Fdx = dc*cvx, Fdy = dc*cvy, Fdz = dc*cvz;

        float dvx = (Fex + Fdx + Fcx) * invm;
        float dvy = (Fey + Fdy + Fcy) * invm;
        float dvz = (Fez - m*G_ACC + Fdz + Fcz) * invm;

        if (s == 0 && q == 0) {   // forces output needs only k1: write now
            ob[832 + i*3+0] = Fex + m*dvx;
            ob[832 + i*3+1] = Fey + m*dvy;
            ob[832 + i*3+2] = Fez + m*dvz;
        }

        float dqw = 0.5f*(-crx*cox - cry*coy - crz*coz);
        float dqx = 0.5f*( crw*cox + cry*coz - crz*coy);
        float dqy = 0.5f*( crw*coy - crx*coz + crz*cox);
        float dqz = 0.5f*( crw*coz + crx*coy - cry*cox);

        float Iox = Ix*cox, Ioy = Iy*coy, Ioz = Iz*coz;
        float dwx = (tx - (coy*Ioz - coz*Ioy)) * iIx;
        float dwy = (ty - (coz*Iox - cox*Ioz)) * iIy;
        float dwz = (tz - (cox*Ioy - coy*Iox)) * iIz;

        float ei = (Fex+Fdx)*cvx + (Fey+Fdy)*cvy + (Fez+Fdz)*cvz;
        #pragma unroll
        for (int off = 32; off > 0; off >>= 1) ei += __shfl_xor(ei, off, 64);

        const float w = (s == 0 || s == 3) ? 1.f : 2.f;
        eacc += w * ei;
        apx += w*cvx; apy += w*cvy; apz += w*cvz;
        avx += w*dvx; avy += w*dvy; avz += w*dvz;
        arw += w*dqw; arx += w*dqx; ary += w*dqy; arz += w*dqz;
        awx += w*dwx; awy += w*dwy; awz += w*dwz;

        if (s < 3) {
            const float h = (s == 2) ? DT : DT*0.5f;
            float npx = bpx + h*cvx, npy = bpy + h*cvy, npz = bpz + h*cvz;
            cvx = bvx + h*dvx; cvy = bvy + h*dvy; cvz = bvz + h*dvz;
            cpx = npx; cpy = npy; cpz = npz;
            float qw = brw + h*dqw, qx = brx + h*dqx, qy = bry + h*dqy, qz = brz + h*dqz;
            float iqn = 1.0f / fmaxf(sqrtf(qw*qw+qx*qx+qy*qy+qz*qz), 1e-12f);
            crw = qw*iqn; crx = qx*iqn; cry = qy*iqn; crz = qz*iqn;
            cox = box + h*dwx; coy = boy + h*dwy; coz = boz + h*dwz;
            __syncthreads();   // WAR: sF reads done before next stage's writes
        }
    }

    if (q == 0) {
        const float s6 = DT / 6.0f;
        ob[      i*3+0] = bpx + s6*apx;  ob[      i*3+1] = bpy + s6*apy;  ob[      i*3+2] = bpz + s6*apz;
        ob[192 + i*3+0] = bvx + s6*avx;  ob[192 + i*3+1] = bvy + s6*avy;  ob[192 + i*3+2] = bvz + s6*avz;
        {
            float qw=brw+s6*arw, qx=brx+s6*arx, qy=bry+s6*ary, qz=brz+s6*arz;
            float iq = 1.0f / fmaxf(sqrtf(qw*qw+qx*qx+qy*qy+qz*qz), 1e-12f);
            ob[384 + i*4+0]=qw*iq; ob[384 + i*4+1]=qx*iq; ob[384 + i*4+2]=qy*iq; ob[384 + i*4+3]=qz*iq;
        }
        ob[640 + i*3+0] = box + s6*awx;  ob[640 + i*3+1] = boy + s6*awy;  ob[640 + i*3+2] = boz + s6*awz;
        if (i == 0) ob[1024] = energy[b] + s6*eacc;
    }
}

extern "C" void kernel_launch(void* const* d_in, const int* in_sizes, int n_in,
                              void* d_out, int out_size, void* d_ws, size_t ws_size,
                              hipStream_t stream) {
    const float* pos      = (const float*)d_in[0];
    const float* vel      = (const float*)d_in[1];
    const float* rot      = (const float*)d_in[2];
    const float* omega    = (const float*)d_in[3];
    const float* mass     = (const float*)d_in[4];
    const float* inertia  = (const float*)d_in[5];
    const float* contacts = (const float*)d_in[6];
    const float* energy   = (const float*)d_in[7];
    const float* fluid_v  = (const float*)d_in[8];
    const float* Fext     = (const float*)d_in[9];
    const float* tau      = (const float*)d_in[10];
    const float* log_A    = (const float*)d_in[11];
    const float* log_k    = (const float*)d_in[12];
    const float* log_b    = (const float*)d_in[13];
    const float* conv_w   = (const float*)d_in[14];
    float* out = (float*)d_out;

    fused_kernel<<<dim3(2048), dim3(256), 0, stream>>>(
        pos, vel, rot, omega, mass, inertia, contacts, energy, fluid_v,
        Fext, tau, log_A, log_k, log_b, conv_w, out);
}

// Round 5
// 434.690 us; speedup vs baseline: 1.3086x; 1.3086x over previous
//
#include <hip/hip_runtime.h>

#define DT (1.0f/60.0f)
#define G_ACC 9.81f
#define RHO 1.225f
#define CD_ 0.47f
#define NU 0.001f

__device__ __forceinline__ float softplus_f(float x) {
    return log1pf(expf(-fabsf(x))) + fmaxf(x, 0.0f);
}

// readlane: lane index is wave-uniform (q*16+jj, q uniform per wave)
#define RL(v, l) __int_as_float(__builtin_amdgcn_readlane(__float_as_int(v), (l)))
// force a block-uniform float into an SGPR
#define SLANE(x) __int_as_float(__builtin_amdgcn_readfirstlane(__float_as_int(x)))

// DPP x-shifts within 16-lane rows (x = lane&15); bound_ctrl=1 -> 0 at edges
__device__ __forceinline__ float dpp_xm(float v) { // from x-1, 0 at x==0
    return __int_as_float(__builtin_amdgcn_update_dpp(0, __float_as_int(v), 0x111, 0xf, 0xf, true));
}
__device__ __forceinline__ float dpp_xp(float v) { // from x+1, 0 at x==15
    return __int_as_float(__builtin_amdgcn_update_dpp(0, __float_as_int(v), 0x101, 0xf, 0xf, true));
}

// grid = 2048 x 256: blocks [0,1536) fluid (ch=blk>>9, b=blk&511),
// [1536,2048) particle.
// launch_bounds(256,5): cap ~102 VGPR. (256,8) forced VGPR=32 and spilled
// base/acc/o/W to scratch -> 1.6 GB HBM traffic, 478 us (R4). The kernel
// genuinely needs ~90 VGPRs; do not demand more than 5 waves/EU here.
__global__ __launch_bounds__(256, 5) void fused_kernel(
    const float* __restrict__ pos, const float* __restrict__ vel,
    const float* __restrict__ rot, const float* __restrict__ omega,
    const float* __restrict__ mass, const float* __restrict__ inertia,
    const float* __restrict__ contacts, const float* __restrict__ energy,
    const float* __restrict__ fluid, const float* __restrict__ Fext,
    const float* __restrict__ tau, const float* __restrict__ log_A,
    const float* __restrict__ log_k, const float* __restrict__ log_b,
    const float* __restrict__ conv_w, float* __restrict__ out)
{
    __shared__ float smem[4928];   // fluid: u[4352]+zcol[16]+red[4]; particle: cont[4160]+sF[768]
    const int t = threadIdx.x;

    if (blockIdx.x < 1536) {
        // ================= FLUID =================
        const int b  = blockIdx.x & 511;
        const int ch = blockIdx.x >> 9;
        const int x  = t & 15, y = t >> 4, wv = t >> 6;
        float* u   = smem;                 // col*17 + z  (17 odd -> conflict-free)
        float* red = smem + 4368;
        if (t < 16) smem[4352 + t] = 0.f;  // zero column for y-edge padding

        // weights -> SGPRs, NU pre-folded
        float W[27];
        #pragma unroll
        for (int k = 0; k < 27; ++k) W[k] = NU * SLANE(conv_w[ch*27 + k]);

        const int lb = t*17;
        const float* fb = fluid + (size_t)b*12288 + 3*t + ch;
        float base[16], acc[16];
        #pragma unroll
        for (int z = 0; z < 16; ++z) {
            float v = fb[z*768];
            base[z] = v; acc[z] = 0.f; u[lb + z] = v;
        }

        // valid-tap weight sums (already NU-scaled): k = o - mean*Sz
        const float xm = (x > 0) ? 1.f : 0.f, xp = (x < 15) ? 1.f : 0.f;
        const float mm = (y > 0) ? 1.f : 0.f, pm = (y < 15) ? 1.f : 0.f;
        float Sdz0, Sdz1, Sdz2;
        {
            float a0 = W[0]*xm + W[1] + W[2]*xp;
            float a1 = W[3]*xm + W[4] + W[5]*xp;
            float a2 = W[6]*xm + W[7] + W[8]*xp;
            Sdz0 = mm*a0 + a1 + pm*a2;
            a0 = W[ 9]*xm + W[10] + W[11]*xp;
            a1 = W[12]*xm + W[13] + W[14]*xp;
            a2 = W[15]*xm + W[16] + W[17]*xp;
            Sdz1 = mm*a0 + a1 + pm*a2;
            a0 = W[18]*xm + W[19] + W[20]*xp;
            a1 = W[21]*xm + W[22] + W[23]*xp;
            a2 = W[24]*xm + W[25] + W[26]*xp;
            Sdz2 = mm*a0 + a1 + pm*a2;
        }
        const float SzLo = Sdz1 + Sdz2, SzHi = Sdz0 + Sdz1, SzMid = Sdz0 + Sdz1 + Sdz2;
        const int cm = (y > 0)  ? lb - 272 : 4352;   // zero column at edges
        const int cp = (y < 15) ? lb + 272 : 4352;

        __syncthreads();                             // B1: planes + zero col ready
        float mean = 0.f;

        // scatter-form z-conv: value at z feeds o[z-1],o[z],o[z+1]
        #define SEC(ca, dy) { \
            _Pragma("unroll") \
            for (int z = 0; z < 16; ++z) { \
                float c  = u[(ca) + z]; \
                float cl = dpp_xm(c), cr = dpp_xp(c); \
                o[z] += W[9+(dy)*3+1]*c + W[9+(dy)*3]*cl + W[9+(dy)*3+2]*cr; \
                if (z < 15) o[z+1] += W[(dy)*3+1]*c + W[(dy)*3]*cl + W[(dy)*3+2]*cr; \
                if (z > 0)  o[z-1] += W[18+(dy)*3+1]*c + W[18+(dy)*3]*cl + W[18+(dy)*3+2]*cr; \
            } }

        #pragma unroll
        for (int s = 0; s < 4; ++s) {
            float o[16];
            #pragma unroll
            for (int z = 0; z < 16; ++z) o[z] = 0.f;
            SEC(lb, 1);   // dy = 0
            SEC(cm, 0);   // dy = -1 (zero col at y==0)
            SEC(cp, 2);   // dy = +1

            if (s < 3) {
                const float h = (s == 2) ? DT : DT*0.5f;
                const float w = (s == 0) ? 1.f : 2.f;
                float ps = 0.f;
                #pragma unroll
                for (int z = 0; z < 16; ++z) {
                    float Sz = (z == 0) ? SzLo : ((z == 15) ? SzHi : SzMid);
                    float k = o[z] - mean * Sz;
                    acc[z] += w * k;
                    float v = base[z] + h * k;
                    o[z] = v; ps += v;
                }
                #pragma unroll
                for (int off = 32; off > 0; off >>= 1) ps += __shfl_xor(ps, off, 64);
                __syncthreads();             // WAR: all conv reads of state s done
                #pragma unroll
                for (int z = 0; z < 16; ++z) u[lb + z] = o[z];
                if ((t & 63) == 0) red[wv] = ps;
                __syncthreads();             // writes + red visible
                mean = (red[0] + red[1] + red[2] + red[3]) * (1.0f/4096.0f);
            } else {
                #pragma unroll
                for (int z = 0; z < 16; ++z) {
                    float Sz = (z == 0) ? SzLo : ((z == 15) ? SzHi : SzMid);
                    acc[z] += o[z] - mean * Sz;
                }
            }
        }
        #undef SEC

        float ps = 0.f;
        float o[16];
        #pragma unroll
        for (int z = 0; z < 16; ++z) { o[z] = base[z] + (DT/6.0f)*acc[z]; ps += o[z]; }
        #pragma unroll
        for (int off = 32; off > 0; off >>= 1) ps += __shfl_xor(ps, off, 64);
        __syncthreads();                     // WAR on red vs stage-2 mean reads
        if ((t & 63) == 0) red[wv] = ps;
        __syncthreads();
        const float mn = (red[0] + red[1] + red[2] + red[3]) * (1.0f/4096.0f);

        float* ob = out + (size_t)b*13313 + 1025 + 3*t + ch;
        #pragma unroll
        for (int z = 0; z < 16; ++z) ob[z*768] = o[z] - mn;
        return;
    }

    // ================= PARTICLE =================
    const int b = blockIdx.x - 1536;
    const int q = t >> 6;       // j-chunk / wave id
    const int i = t & 63;       // particle id
    float* cont = smem;         // [i*65 + j] : 65 odd -> 2-way (free)
    float* sF   = smem + 4160;  // [q*192 + i*3 + c]

    {   // cooperative coalesced load of contacts into LDS
        const float4* cg = (const float4*)(contacts + (size_t)b*4096);
        #pragma unroll
        for (int v = 0; v < 4; ++v) {
            float4 c4 = cg[v*256 + t];
            int fi = (v*256 + t) * 4;
            int r = fi >> 6, cc = fi & 63;
            float* p = cont + r*65 + cc;
            p[0] = c4.x; p[1] = c4.y; p[2] = c4.z; p[3] = c4.w;
        }
    }

    const size_t p3 = ((size_t)b*64 + i)*3;
    const size_t p4 = ((size_t)b*64 + i)*4;
    float bpx=pos[p3],   bpy=pos[p3+1],   bpz=pos[p3+2];
    float bvx=vel[p3],   bvy=vel[p3+1],   bvz=vel[p3+2];
    float brw=rot[p4],   brx=rot[p4+1],   bry=rot[p4+2],  brz=rot[p4+3];
    float box=omega[p3], boy=omega[p3+1], boz=omega[p3+2];
    float m  = mass[(size_t)b*64+i];
    float Ix=inertia[p3], Iy=inertia[p3+1], Iz=inertia[p3+2];
    float Fex=Fext[p3],   Fey=Fext[p3+1],   Fez=Fext[p3+2];
    float tx=tau[p3],     ty=tau[p3+1],     tz=tau[p3+2];
    float dragc = -0.5f * RHO * CD_ * softplus_f(log_A[i]);
    float kc = softplus_f(SLANE(log_k[0]));
    float bc = softplus_f(SLANE(log_b[0]));
    float invm = 1.0f / m;
    float iIx = 1.0f/fmaxf(Ix,1e-6f), iIy = 1.0f/fmaxf(Iy,1e-6f), iIz = 1.0f/fmaxf(Iz,1e-6f);

    float cpx=bpx, cpy=bpy, cpz=bpz;
    float cvx=bvx, cvy=bvy, cvz=bvz;
    float crw=brw, crx=brx, cry=bry, crz=brz;
    float cox=box, coy=boy, coz=boz;

    float apx=0,apy=0,apz=0, avx=0,avy=0,avz=0;
    float arw=0,arx=0,ary=0,arz=0, awx=0,awy=0,awz=0;
    float eacc=0.f;

    const int j0 = q << 4;
    float* ob = out + (size_t)b * 13313;
    __syncthreads();   // contacts staged

    #pragma unroll
    for (int s = 0; s < 4; ++s) {
        float Fcx=0.f, Fcy=0.f, Fcz=0.f;
        #pragma unroll
        for (int jj = 0; jj < 16; ++jj) {
            const int j = j0 + jj;
            float pjx = RL(cpx, j), pjy = RL(cpy, j), pjz = RL(cpz, j);
            float vjx = RL(cvx, j), vjy = RL(cvy, j), vjz = RL(cvz, j);
            float dx = pjx - cpx, dy = pjy - cpy, dz = pjz - cpz;
            float dist = fmaxf(sqrtf(dx*dx + dy*dy + dz*dz), 1e-6f);
            float pen  = fmaxf(1.0f - dist, 0.0f);
            float coef = kc * pen * __builtin_amdgcn_rcpf(dist);
            float cbj  = bc * cont[i*65 + j];
            Fcx += coef*dx + cbj*(vjx - cvx);
            Fcy += coef*dy + cbj*(vjy - cvy);
            Fcz += coef*dz + cbj*(vjz - cvz);
        }
        sF[q*192 + i*3+0] = Fcx;
        sF[q*192 + i*3+1] = Fcy;
        sF[q*192 + i*3+2] = Fcz;
        __syncthreads();
        Fcx = sF[i*3+0] + sF[192+i*3+0] + sF[384+i*3+0] + sF[576+i*3+0];
        Fcy = sF[i*3+1] + sF[192+i*3+1] + sF[384+i*3+1] + sF[576+i*3+1];
        Fcz = sF[i*3+2] + sF[192+i*3+2] + sF[384+i*3+2] + sF[576+i*3+2];

        float vm = fmaxf(sqrtf(cvx*cvx+cvy*cvy+cvz*cvz), 1e-6f);
        float dc = dragc * vm;
        float Fdx = dc*cvx, Fdy = dc*cvy, Fdz = dc*cvz;

        float dvx = (Fex + Fdx + Fcx) * invm;
        float dvy = (Fey + Fdy + Fcy) * invm;
        float dvz = (Fez - m*G_ACC + Fdz + Fcz) * invm;

        if (s == 0 && q == 0) {   // forces output needs only k1: write now
            ob[832 + i*3+0] = Fex + m*dvx;
            ob[832 + i*3+1] = Fey + m*dvy;
            ob[832 + i*3+2] = Fez + m*dvz;
        }

        float dqw = 0.5f*(-crx*cox - cry*coy - crz*coz);
        float dqx = 0.5f*( crw*cox + cry*coz - crz*coy);
        float dqy = 0.5f*( crw*coy - crx*coz + crz*cox);
        float dqz = 0.5f*( crw*coz + crx*coy - cry*cox);

        float Iox = Ix*cox, Ioy = Iy*coy, Ioz = Iz*coz;
        float dwx = (tx - (coy*Ioz - coz*Ioy)) * iIx;
        float dwy = (ty - (coz*Iox - cox*Ioz)) * iIy;
        float dwz = (tz - (cox*Ioy - coy*Iox)) * iIz;

        float ei = (Fex+Fdx)*cvx + (Fey+Fdy)*cvy + (Fez+Fdz)*cvz;
        #pragma unroll
        for (int off = 32; off > 0; off >>= 1) ei += __shfl_xor(ei, off, 64);

        const float w = (s == 0 || s == 3) ? 1.f : 2.f;
        eacc += w * ei;
        apx += w*cvx; apy += w*cvy; apz += w*cvz;
        avx += w*dvx; avy += w*dvy; avz += w*dvz;
        arw += w*dqw; arx += w*dqx; ary += w*dqy; arz += w*dqz;
        awx += w*dwx; awy += w*dwy; awz += w*dwz;

        if (s < 3) {
            const float h = (s == 2) ? DT : DT*0.5f;
            float npx = bpx + h*cvx, npy = bpy + h*cvy, npz = bpz + h*cvz;
            cvx = bvx + h*dvx; cvy = bvy + h*dvy; cvz = bvz + h*dvz;
            cpx = npx; cpy = npy; cpz = npz;
            float qw = brw + h*dqw, qx = brx + h*dqx, qy = bry + h*dqy, qz = brz + h*dqz;
            float iqn = 1.0f / fmaxf(sqrtf(qw*qw+qx*qx+qy*qy+qz*qz), 1e-12f);
            crw = qw*iqn; crx = qx*iqn; cry = qy*iqn; crz = qz*iqn;
            cox = box + h*dwx; coy = boy + h*dwy; coz = boz + h*dwz;
            __syncthreads();   // WAR: sF reads done before next stage's writes
        }
    }

    if (q == 0) {
        const float s6 = DT / 6.0f;
        ob[      i*3+0] = bpx + s6*apx;  ob[      i*3+1] = bpy + s6*apy;  ob[      i*3+2] = bpz + s6*apz;
        ob[192 + i*3+0] = bvx + s6*avx;  ob[192 + i*3+1] = bvy + s6*avy;  ob[192 + i*3+2] = bvz + s6*avz;
        {
            float qw=brw+s6*arw, qx=brx+s6*arx, qy=bry+s6*ary, qz=brz+s6*arz;
            float iq = 1.0f / fmaxf(sqrtf(qw*qw+qx*qx+qy*qy+qz*qz), 1e-12f);
            ob[384 + i*4+0]=qw*iq; ob[384 + i*4+1]=qx*iq; ob[384 + i*4+2]=qy*iq; ob[384 + i*4+3]=qz*iq;
        }
        ob[640 + i*3+0] = box + s6*awx;  ob[640 + i*3+1] = boy + s6*awy;  ob[640 + i*3+2] = boz + s6*awz;
        if (i == 0) ob[1024] = energy[b] + s6*eacc;
    }
}

extern "C" void kernel_launch(void* const* d_in, const int* in_sizes, int n_in,
                              void* d_out, int out_size, void* d_ws, size_t ws_size,
                              hipStream_t stream) {
    const float* pos      = (const float*)d_in[0];
    const float* vel      = (const float*)d_in[1];
    const float* rot      = (const float*)d_in[2];
    const float* omega    = (const float*)d_in[3];
    const float* mass     = (const float*)d_in[4];
    const float* inertia  = (const float*)d_in[5];
    const float* contacts = (const float*)d_in[6];
    const float* energy   = (const float*)d_in[7];
    const float* fluid_v  = (const float*)d_in[8];
    const float* Fext     = (const float*)d_in[9];
    const float* tau      = (const float*)d_in[10];
    const float* log_A    = (const float*)d_in[11];
    const float* log_k    = (const float*)d_in[12];
    const float* log_b    = (const float*)d_in[13];
    const float* conv_w   = (const float*)d_in[14];
    float* out = (float*)d_out;

    fused_kernel<<<dim3(2048), dim3(256), 0, stream>>>(
        pos, vel, rot, omega, mass, inertia, contacts, energy, fluid_v,
        Fext, tau, log_A, log_k, log_b, conv_w, out);
}

// Round 6
// 187.091 us; speedup vs baseline: 3.0405x; 2.3234x over previous
//
#include <hip/hip_runtime.h>

#define DT (1.0f/60.0f)
#define G_ACC 9.81f
#define RHO 1.225f
#define CD_ 0.47f
#define NU 0.001f

__device__ __forceinline__ float softplus_f(float x) {
    return log1pf(expf(-fabsf(x))) + fmaxf(x, 0.0f);
}

// readlane: lane index is wave-uniform (q*16+jj, q uniform per wave)
#define RL(v, l) __int_as_float(__builtin_amdgcn_readlane(__float_as_int(v), (l)))
// force a block-uniform float into an SGPR
#define SLANE(x) __int_as_float(__builtin_amdgcn_readfirstlane(__float_as_int(x)))

// DPP x-shifts within 16-lane rows (x = lane&15); bound_ctrl=1 -> 0 at edges
__device__ __forceinline__ float dpp_xm(float v) { // from x-1, 0 at x==0
    return __int_as_float(__builtin_amdgcn_update_dpp(0, __float_as_int(v), 0x111, 0xf, 0xf, true));
}
__device__ __forceinline__ float dpp_xp(float v) { // from x+1, 0 at x==15
    return __int_as_float(__builtin_amdgcn_update_dpp(0, __float_as_int(v), 0x101, 0xf, 0xf, true));
}

// grid = 2048 x 256: blocks [0,1536) fluid (ch=blk>>9, b=blk&511),
// [1536,2048) particle.
// LAUNCH BOUNDS WARNING (R4/R5 measured): adding a min-waves second arg
// ((256,8) or even (256,5)) makes the allocator clamp VGPR to 32/48 and
// spill base/acc/o/W to scratch -> 0.6-1.6 GB HBM traffic, 6-8x slower.
// Plain (256) compiles to ~88 VGPR, zero spill (R3: 64 us dispatch).
__global__ __launch_bounds__(256) void fused_kernel(
    const float* __restrict__ pos, const float* __restrict__ vel,
    const float* __restrict__ rot, const float* __restrict__ omega,
    const float* __restrict__ mass, const float* __restrict__ inertia,
    const float* __restrict__ contacts, const float* __restrict__ energy,
    const float* __restrict__ fluid, const float* __restrict__ Fext,
    const float* __restrict__ tau, const float* __restrict__ log_A,
    const float* __restrict__ log_k, const float* __restrict__ log_b,
    const float* __restrict__ conv_w, float* __restrict__ out)
{
    __shared__ float smem[4928];   // fluid: u[4352]+zcol[16]+red[4]; particle: cont[4160]+sF[768]
    const int t = threadIdx.x;

    if (blockIdx.x < 1536) {
        // ================= FLUID =================
        const int b  = blockIdx.x & 511;
        const int ch = blockIdx.x >> 9;
        const int x  = t & 15, y = t >> 4, wv = t >> 6;
        float* u   = smem;                 // col*17 + z  (17 odd -> conflict-free)
        float* red = smem + 4368;
        if (t < 16) smem[4352 + t] = 0.f;  // zero column for y-edge padding

        // weights -> SGPRs, NU pre-folded
        float W[27];
        #pragma unroll
        for (int k = 0; k < 27; ++k) W[k] = NU * SLANE(conv_w[ch*27 + k]);

        const int lb = t*17;
        const float* fb = fluid + (size_t)b*12288 + 3*t + ch;
        float base[16], acc[16];
        #pragma unroll
        for (int z = 0; z < 16; ++z) {
            float v = fb[z*768];
            base[z] = v; acc[z] = 0.f; u[lb + z] = v;
        }

        // valid-tap weight sums (already NU-scaled): k = o - mean*Sz
        const float xm = (x > 0) ? 1.f : 0.f, xp = (x < 15) ? 1.f : 0.f;
        const float mm = (y > 0) ? 1.f : 0.f, pm = (y < 15) ? 1.f : 0.f;
        float Sdz0, Sdz1, Sdz2;
        {
            float a0 = W[0]*xm + W[1] + W[2]*xp;
            float a1 = W[3]*xm + W[4] + W[5]*xp;
            float a2 = W[6]*xm + W[7] + W[8]*xp;
            Sdz0 = mm*a0 + a1 + pm*a2;
            a0 = W[ 9]*xm + W[10] + W[11]*xp;
            a1 = W[12]*xm + W[13] + W[14]*xp;
            a2 = W[15]*xm + W[16] + W[17]*xp;
            Sdz1 = mm*a0 + a1 + pm*a2;
            a0 = W[18]*xm + W[19] + W[20]*xp;
            a1 = W[21]*xm + W[22] + W[23]*xp;
            a2 = W[24]*xm + W[25] + W[26]*xp;
            Sdz2 = mm*a0 + a1 + pm*a2;
        }
        const float SzLo = Sdz1 + Sdz2, SzHi = Sdz0 + Sdz1, SzMid = Sdz0 + Sdz1 + Sdz2;
        const int cm = (y > 0)  ? lb - 272 : 4352;   // zero column at edges
        const int cp = (y < 15) ? lb + 272 : 4352;

        __syncthreads();                             // B1: planes + zero col ready
        float mean = 0.f;

        // scatter-form z-conv: value at z feeds o[z-1],o[z],o[z+1]
        #define SEC(ca, dy) { \
            _Pragma("unroll") \
            for (int z = 0; z < 16; ++z) { \
                float c  = u[(ca) + z]; \
                float cl = dpp_xm(c), cr = dpp_xp(c); \
                o[z] += W[9+(dy)*3+1]*c + W[9+(dy)*3]*cl + W[9+(dy)*3+2]*cr; \
                if (z < 15) o[z+1] += W[(dy)*3+1]*c + W[(dy)*3]*cl + W[(dy)*3+2]*cr; \
                if (z > 0)  o[z-1] += W[18+(dy)*3+1]*c + W[18+(dy)*3]*cl + W[18+(dy)*3+2]*cr; \
            } }

        #pragma unroll
        for (int s = 0; s < 4; ++s) {
            float o[16];
            #pragma unroll
            for (int z = 0; z < 16; ++z) o[z] = 0.f;
            SEC(lb, 1);   // dy = 0
            SEC(cm, 0);   // dy = -1 (zero col at y==0)
            SEC(cp, 2);   // dy = +1

            if (s < 3) {
                const float h = (s == 2) ? DT : DT*0.5f;
                const float w = (s == 0) ? 1.f : 2.f;
                float ps = 0.f;
                #pragma unroll
                for (int z = 0; z < 16; ++z) {
                    float Sz = (z == 0) ? SzLo : ((z == 15) ? SzHi : SzMid);
                    float k = o[z] - mean * Sz;
                    acc[z] += w * k;
                    float v = base[z] + h * k;
                    o[z] = v; ps += v;
                }
                #pragma unroll
                for (int off = 32; off > 0; off >>= 1) ps += __shfl_xor(ps, off, 64);
                __syncthreads();             // WAR: all conv reads of state s done
                #pragma unroll
                for (int z = 0; z < 16; ++z) u[lb + z] = o[z];
                if ((t & 63) == 0) red[wv] = ps;
                __syncthreads();             // writes + red visible
                mean = (red[0] + red[1] + red[2] + red[3]) * (1.0f/4096.0f);
            } else {
                #pragma unroll
                for (int z = 0; z < 16; ++z) {
                    float Sz = (z == 0) ? SzLo : ((z == 15) ? SzHi : SzMid);
                    acc[z] += o[z] - mean * Sz;
                }
            }
        }
        #undef SEC

        float ps = 0.f;
        float o[16];
        #pragma unroll
        for (int z = 0; z < 16; ++z) { o[z] = base[z] + (DT/6.0f)*acc[z]; ps += o[z]; }
        #pragma unroll
        for (int off = 32; off > 0; off >>= 1) ps += __shfl_xor(ps, off, 64);
        __syncthreads();                     // WAR on red vs stage-2 mean reads
        if ((t & 63) == 0) red[wv] = ps;
        __syncthreads();
        const float mn = (red[0] + red[1] + red[2] + red[3]) * (1.0f/4096.0f);

        float* ob = out + (size_t)b*13313 + 1025 + 3*t + ch;
        #pragma unroll
        for (int z = 0; z < 16; ++z) ob[z*768] = o[z] - mn;
        return;
    }

    // ================= PARTICLE =================
    const int b = blockIdx.x - 1536;
    const int q = t >> 6;       // j-chunk / wave id
    const int i = t & 63;       // particle id
    float* cont = smem;         // [i*65 + j] : 65 odd -> 2-way (free)
    float* sF   = smem + 4160;  // [q*192 + i*3 + c]

    {   // cooperative coalesced load of contacts into LDS
        const float4* cg = (const float4*)(contacts + (size_t)b*4096);
        #pragma unroll
        for (int v = 0; v < 4; ++v) {
            float4 c4 = cg[v*256 + t];
            int fi = (v*256 + t) * 4;
            int r = fi >> 6, cc = fi & 63;
            float* p = cont + r*65 + cc;
            p[0] = c4.x; p[1] = c4.y; p[2] = c4.z; p[3] = c4.w;
        }
    }

    const size_t p3 = ((size_t)b*64 + i)*3;
    const size_t p4 = ((size_t)b*64 + i)*4;
    float bpx=pos[p3],   bpy=pos[p3+1],   bpz=pos[p3+2];
    float bvx=vel[p3],   bvy=vel[p3+1],   bvz=vel[p3+2];
    float brw=rot[p4],   brx=rot[p4+1],   bry=rot[p4+2],  brz=rot[p4+3];
    float box=omega[p3], boy=omega[p3+1], boz=omega[p3+2];
    float m  = mass[(size_t)b*64+i];
    float Ix=inertia[p3], Iy=inertia[p3+1], Iz=inertia[p3+2];
    float Fex=Fext[p3],   Fey=Fext[p3+1],   Fez=Fext[p3+2];
    float tx=tau[p3],     ty=tau[p3+1],     tz=tau[p3+2];
    float dragc = -0.5f * RHO * CD_ * softplus_f(log_A[i]);
    float kc = softplus_f(SLANE(log_k[0]));
    float bc = softplus_f(SLANE(log_b[0]));
    float invm = 1.0f / m;
    float iIx = 1.0f/fmaxf(Ix,1e-6f), iIy = 1.0f/fmaxf(Iy,1e-6f), iIz = 1.0f/fmaxf(Iz,1e-6f);

    float cpx=bpx, cpy=bpy, cpz=bpz;
    float cvx=bvx, cvy=bvy, cvz=bvz;
    float crw=brw, crx=brx, cry=bry, crz=brz;
    float cox=box, coy=boy, coz=boz;

    float apx=0,apy=0,apz=0, avx=0,avy=0,avz=0;
    float arw=0,arx=0,ary=0,arz=0, awx=0,awy=0,awz=0;
    float eacc=0.f;

    const int j0 = q << 4;
    float* ob = out + (size_t)b * 13313;
    __syncthreads();   // contacts staged

    #pragma unroll
    for (int s = 0; s < 4; ++s) {
        float Fcx=0.f, Fcy=0.f, Fcz=0.f;
        #pragma unroll
        for (int jj = 0; jj < 16; ++jj) {
            const int j = j0 + jj;
            float pjx = RL(cpx, j), pjy = RL(cpy, j), pjz = RL(cpz, j);
            float vjx = RL(cvx, j), vjy = RL(cvy, j), vjz = RL(cvz, j);
            float dx = pjx - cpx, dy = pjy - cpy, dz = pjz - cpz;
            float dist = fmaxf(sqrtf(dx*dx + dy*dy + dz*dz), 1e-6f);
            float pen  = fmaxf(1.0f - dist, 0.0f);
            float coef = kc * pen * __builtin_amdgcn_rcpf(dist);
            float cbj  = bc * cont[i*65 + j];
            Fcx += coef*dx + cbj*(vjx - cvx);
            Fcy += coef*dy + cbj*(vjy - cvy);
            Fcz += coef*dz + cbj*(vjz - cvz);
        }
        sF[q*192 + i*3+0] = Fcx;
        sF[q*192 + i*3+1] = Fcy;
        sF[q*192 + i*3+2] = Fcz;
        __syncthreads();
        Fcx = sF[i*3+0] + sF[192+i*3+0] + sF[384+i*3+0] + sF[576+i*3+0];
        Fcy = sF[i*3+1] + sF[192+i*3+1] + sF[384+i*3+1] + sF[576+i*3+1];
        Fcz = sF[i*3+2] + sF[192+i*3+2] + sF[384+i*3+2] + sF[576+i*3+2];

        float vm = fmaxf(sqrtf(cvx*cvx+cvy*cvy+cvz*cvz), 1e-6f);
        float dc = dragc * vm;
        float Fdx = dc*cvx, Fdy = dc*cvy, Fdz = dc*cvz;

        float dvx = (Fex + Fdx + Fcx) * invm;
        float dvy = (Fey + Fdy + Fcy) * invm;
        float dvz = (Fez - m*G_ACC + Fdz + Fcz) * invm;

        if (s == 0 && q == 0) {   // forces output needs only k1: write now
            ob[832 + i*3+0] = Fex + m*dvx;
            ob[832 + i*3+1] = Fey + m*dvy;
            ob[832 + i*3+2] = Fez + m*dvz;
        }

        float dqw = 0.5f*(-crx*cox - cry*coy - crz*coz);
        float dqx = 0.5f*( crw*cox + cry*coz - crz*coy);
        float dqy = 0.5f*( crw*coy - crx*coz + crz*cox);
        float dqz = 0.5f*( crw*coz + crx*coy - cry*cox);

        float Iox = Ix*cox, Ioy = Iy*coy, Ioz = Iz*coz;
        float dwx = (tx - (coy*Ioz - coz*Ioy)) * iIx;
        float dwy = (ty - (coz*Iox - cox*Ioz)) * iIy;
        float dwz = (tz - (cox*Ioy - coy*Iox)) * iIz;

        float ei = (Fex+Fdx)*cvx + (Fey+Fdy)*cvy + (Fez+Fdz)*cvz;
        #pragma unroll
        for (int off = 32; off > 0; off >>= 1) ei += __shfl_xor(ei, off, 64);

        const float w = (s == 0 || s == 3) ? 1.f : 2.f;
        eacc += w * ei;
        apx += w*cvx; apy += w*cvy; apz += w*cvz;
        avx += w*dvx; avy += w*dvy; avz += w*dvz;
        arw += w*dqw; arx += w*dqx; ary += w*dqy; arz += w*dqz;
        awx += w*dwx; awy += w*dwy; awz += w*dwz;

        if (s < 3) {
            const float h = (s == 2) ? DT : DT*0.5f;
            float npx = bpx + h*cvx, npy = bpy + h*cvy, npz = bpz + h*cvz;
            cvx = bvx + h*dvx; cvy = bvy + h*dvy; cvz = bvz + h*dvz;
            cpx = npx; cpy = npy; cpz = npz;
            float qw = brw + h*dqw, qx = brx + h*dqx, qy = bry + h*dqy, qz = brz + h*dqz;
            float iqn = 1.0f / fmaxf(sqrtf(qw*qw+qx*qx+qy*qy+qz*qz), 1e-12f);
            crw = qw*iqn; crx = qx*iqn; cry = qy*iqn; crz = qz*iqn;
            cox = box + h*dwx; coy = boy + h*dwy; coz = boz + h*dwz;
            __syncthreads();   // WAR: sF reads done before next stage's writes
        }
    }

    if (q == 0) {
        const float s6 = DT / 6.0f;
        ob[      i*3+0] = bpx + s6*apx;  ob[      i*3+1] = bpy + s6*apy;  ob[      i*3+2] = bpz + s6*apz;
        ob[192 + i*3+0] = bvx + s6*avx;  ob[192 + i*3+1] = bvy + s6*avy;  ob[192 + i*3+2] = bvz + s6*avz;
        {
            float qw=brw+s6*arw, qx=brx+s6*arx, qy=bry+s6*ary, qz=brz+s6*arz;
            float iq = 1.0f / fmaxf(sqrtf(qw*qw+qx*qx+qy*qy+qz*qz), 1e-12f);
            ob[384 + i*4+0]=qw*iq; ob[384 + i*4+1]=qx*iq; ob[384 + i*4+2]=qy*iq; ob[384 + i*4+3]=qz*iq;
        }
        ob[640 + i*3+0] = box + s6*awx;  ob[640 + i*3+1] = boy + s6*awy;  ob[640 + i*3+2] = boz + s6*awz;
        if (i == 0) ob[1024] = energy[b] + s6*eacc;
    }
}

extern "C" void kernel_launch(void* const* d_in, const int* in_sizes, int n_in,
                              void* d_out, int out_size, void* d_ws, size_t ws_size,
                              hipStream_t stream) {
    const float* pos      = (const float*)d_in[0];
    const float* vel      = (const float*)d_in[1];
    const float* rot      = (const float*)d_in[2];
    const float* omega    = (const float*)d_in[3];
    const float* mass     = (const float*)d_in[4];
    const float* inertia  = (const float*)d_in[5];
    const float* contacts = (const float*)d_in[6];
    const float* energy   = (const float*)d_in[7];
    const float* fluid_v  = (const float*)d_in[8];
    const float* Fext     = (const float*)d_in[9];
    const float* tau      = (const float*)d_in[10];
    const float* log_A    = (const float*)d_in[11];
    const float* log_k    = (const float*)d_in[12];
    const float* log_b    = (const float*)d_in[13];
    const float* conv_w   = (const float*)d_in[14];
    float* out = (float*)d_out;

    fused_kernel<<<dim3(2048), dim3(256), 0, stream>>>(
        pos, vel, rot, omega, mass, inertia, contacts, energy, fluid_v,
        Fext, tau, log_A, log_k, log_b, conv_w, out);
}

// Round 7
// 182.278 us; speedup vs baseline: 3.1208x; 1.0264x over previous
//
#include <hip/hip_runtime.h>

#define DT (1.0f/60.0f)
#define G_ACC 9.81f
#define RHO 1.225f
#define CD_ 0.47f
#define NU 0.001f

__device__ __forceinline__ float softplus_f(float x) {
    return log1pf(expf(-fabsf(x))) + fmaxf(x, 0.0f);
}

// readlane: lane index is wave-uniform (q*8+jj, q uniform per wave)
#define RL(v, l) __int_as_float(__builtin_amdgcn_readlane(__float_as_int(v), (l)))
// force a block-uniform float into an SGPR
#define SLANE(x) __int_as_float(__builtin_amdgcn_readfirstlane(__float_as_int(x)))

// DPP x-shifts within 16-lane rows (x = lane&15); bound_ctrl=1 -> 0 at edges
// (= conv zero padding; validated R2-R6)
__device__ __forceinline__ float dpp_xm(float v) { // from x-1, 0 at x==0
    return __int_as_float(__builtin_amdgcn_update_dpp(0, __float_as_int(v), 0x111, 0xf, 0xf, true));
}
__device__ __forceinline__ float dpp_xp(float v) { // from x+1, 0 at x==15
    return __int_as_float(__builtin_amdgcn_update_dpp(0, __float_as_int(v), 0x101, 0xf, 0xf, true));
}

// grid = 2048 x 512: blocks [0,1536) fluid (ch=blk>>9, b=blk&511),
// [1536,2048) particle.
// Fluid: z-split — thread t: col = t&255 (y=col>>4, x=col&15), h = t>>8
// (wave-uniform z-half). Own 8 cells z in [8h, 8h+8). Double-buffered u
// (4370 floats each, incl. 18-float zero pad for y-edges) -> ONE barrier
// per RK4 stage (no WAR barrier; stage s reads buf s&1, writes buf ~(s&1)).
// LAUNCH BOUNDS WARNING (R4/R5 measured): a min-waves 2nd arg makes the
// allocator clamp VGPR (32/48) and spill to scratch (0.6-1.6 GB HBM, 6-8x
// slower). Use plain max-threads form only.
__global__ __launch_bounds__(512) void fused_kernel(
    const float* __restrict__ pos, const float* __restrict__ vel,
    const float* __restrict__ rot, const float* __restrict__ omega,
    const float* __restrict__ mass, const float* __restrict__ inertia,
    const float* __restrict__ contacts, const float* __restrict__ energy,
    const float* __restrict__ fluid, const float* __restrict__ Fext,
    const float* __restrict__ tau, const float* __restrict__ log_A,
    const float* __restrict__ log_k, const float* __restrict__ log_b,
    const float* __restrict__ conv_w, float* __restrict__ out)
{
    // fluid: u0 [0,4370) + u1 [4370,8740) + red[8740,8772) (4 slots x 8)
    // particle: cont [0,4160) + sF [4160,5696)
    __shared__ float smem[8772];
    const int t = threadIdx.x;

    if (blockIdx.x < 1536) {
        // ================= FLUID =================
        const int b   = blockIdx.x & 511;
        const int ch  = blockIdx.x >> 9;
        const int col = t & 255;
        const int h   = t >> 8;            // z-half, wave-uniform
        const int x   = col & 15, y = col >> 4, wv = t >> 6;
        const int h8  = h << 3;
        float* red = smem + 8740;

        // weights -> SGPRs, NU pre-folded
        float W[27];
        #pragma unroll
        for (int k = 0; k < 27; ++k) W[k] = NU * SLANE(conv_w[ch*27 + k]);

        const int lb = col*17;             // column base within a buffer
        if (t < 18) { smem[4352 + t] = 0.f; smem[4370 + 4352 + t] = 0.f; }

        const float* fb = fluid + (size_t)b*12288 + 3*col + ch;
        float base[8], acc[8];
        #pragma unroll
        for (int zz = 0; zz < 8; ++zz) {
            float v = fb[(h8 + zz)*768];
            base[zz] = v; acc[zz] = 0.f;
            smem[lb + h8 + zz] = v;        // init into u0
        }

        // valid-tap weight sums (NU-scaled): k = o - mean*Sz
        const float xm = (x > 0) ? 1.f : 0.f, xp = (x < 15) ? 1.f : 0.f;
        const float mm = (y > 0) ? 1.f : 0.f, pm = (y < 15) ? 1.f : 0.f;
        float Sdz0, Sdz1, Sdz2;
        {
            float a0 = W[0]*xm + W[1] + W[2]*xp;
            float a1 = W[3]*xm + W[4] + W[5]*xp;
            float a2 = W[6]*xm + W[7] + W[8]*xp;
            Sdz0 = mm*a0 + a1 + pm*a2;
            a0 = W[ 9]*xm + W[10] + W[11]*xp;
            a1 = W[12]*xm + W[13] + W[14]*xp;
            a2 = W[15]*xm + W[16] + W[17]*xp;
            Sdz1 = mm*a0 + a1 + pm*a2;
            a0 = W[18]*xm + W[19] + W[20]*xp;
            a1 = W[21]*xm + W[22] + W[23]*xp;
            a2 = W[24]*xm + W[25] + W[26]*xp;
            Sdz2 = mm*a0 + a1 + pm*a2;
        }
        const float SzLo = Sdz1 + Sdz2;            // global z == 0
        const float SzHi = Sdz0 + Sdz1;            // global z == 15
        const float SzMid = Sdz0 + Sdz1 + Sdz2;

        // column-base offsets (relative to read buffer) for z' = h8-1 element
        const int ownR = lb + h8 - 1;
        const int cmR  = (y > 0)  ? (lb - 272 + h8 - 1) : 4353;  // zero pad
        const int cpR  = (y < 15) ? (lb + 272 + h8 - 1) : 4353;

        __syncthreads();                   // init writes + zero pads visible
        float mean = 0.f;

        // load a 10-window (z' = h8-1 .. h8+8) with z-boundary masking;
        // h is wave-uniform so the branch is uniform
        #define LOADC(cidx) { \
            const float* Up = smem + rb + (cidx); \
            if (h == 0) { c[0] = 0.f; \
                _Pragma("unroll") for (int k = 1; k < 10; ++k) c[k] = Up[k]; } \
            else { \
                _Pragma("unroll") for (int k = 0; k < 9; ++k) c[k] = Up[k]; \
                c[9] = 0.f; } }

        // scatter c (src z' = h8-1+k) into o via the 3 z-rows of W, with
        // x-variants from DPP. out local zz: dz=-1 -> k; dz=0 -> k-1; dz=+1 -> k-2
        #define SCAT(wy) { \
            _Pragma("unroll") for (int k = 0; k < 10; ++k) { \
                float cc = c[k], cl = dpp_xm(cc), cr = dpp_xp(cc); \
                if (k < 8) \
                    o[k]   += W[(wy)*3+0]*cl + W[(wy)*3+1]*cc + W[(wy)*3+2]*cr; \
                if (k >= 1 && k <= 8) \
                    o[k-1] += W[9+(wy)*3+0]*cl + W[9+(wy)*3+1]*cc + W[9+(wy)*3+2]*cr; \
                if (k >= 2) \
                    o[k-2] += W[18+(wy)*3+0]*cl + W[18+(wy)*3+1]*cc + W[18+(wy)*3+2]*cr; \
            } }

        #pragma unroll
        for (int s = 0; s < 4; ++s) {
            const int rb = (s & 1) * 4370;         // read buffer
            const int wb = 4370 - rb;              // write buffer
            float o[8];
            #pragma unroll
            for (int zz = 0; zz < 8; ++zz) o[zz] = 0.f;
            {
                float c[10];
                LOADC(ownR); SCAT(1);              // dy = 0
                LOADC(cmR);  SCAT(0);              // dy = -1
                LOADC(cpR);  SCAT(2);              // dy = +1
            }

            if (s < 3) {
                const float hstep = (s == 2) ? DT : DT*0.5f;
                const float w = (s == 0) ? 1.f : 2.f;
                float ps = 0.f;
                #pragma unroll
                for (int zz = 0; zz < 8; ++zz) {
                    float Sz = (h == 0 && zz == 0) ? SzLo
                             : ((h == 1 && zz == 7) ? SzHi : SzMid);
                    float k = o[zz] - mean * Sz;
                    acc[zz] += w * k;
                    float v = base[zz] + hstep * k;
                    smem[wb + lb + h8 + zz] = v;   // other buffer: no WAR
                    ps += v;
                }
                #pragma unroll
                for (int off = 32; off > 0; off >>= 1) ps += __shfl_xor(ps, off, 64);
                if ((t & 63) == 0) red[s*8 + wv] = ps;
                __syncthreads();                   // ONE barrier: u-writes + red
                mean = (red[s*8+0]+red[s*8+1]+red[s*8+2]+red[s*8+3]
                       +red[s*8+4]+red[s*8+5]+red[s*8+6]+red[s*8+7]) * (1.0f/4096.0f);
            } else {
                #pragma unroll
                for (int zz = 0; zz < 8; ++zz) {
                    float Sz = (h == 0 && zz == 0) ? SzLo
                             : ((h == 1 && zz == 7) ? SzHi : SzMid);
                    acc[zz] += o[zz] - mean * Sz;
                }
            }
        }
        #undef LOADC
        #undef SCAT

        float raw[8], ps = 0.f;
        #pragma unroll
        for (int zz = 0; zz < 8; ++zz) { raw[zz] = base[zz] + (DT/6.0f)*acc[zz]; ps += raw[zz]; }
        #pragma unroll
        for (int off = 32; off > 0; off >>= 1) ps += __shfl_xor(ps, off, 64);
        if ((t & 63) == 0) red[24 + wv] = ps;      // slot 3: epilogue-only
        __syncthreads();
        const float mn = (red[24]+red[25]+red[26]+red[27]
                         +red[28]+red[29]+red[30]+red[31]) * (1.0f/4096.0f);

        float* ob = out + (size_t)b*13313 + 1025 + 3*col + ch;
        #pragma unroll
        for (int zz = 0; zz < 8; ++zz) ob[(h8 + zz)*768] = raw[zz] - mn;
        return;
    }

    // ================= PARTICLE =================
    const int b = blockIdx.x - 1536;
    const int q = t >> 6;       // j-chunk / wave id, 0..7 (8 partners each)
    const int i = t & 63;       // particle id
    float* cont = smem;         // [i*65 + j] : 65 odd -> 2-way (free)
    float* sF   = smem + 4160;  // [q*192 + i*3 + c]

    {   // cooperative coalesced load of contacts into LDS
        const float4* cg = (const float4*)(contacts + (size_t)b*4096);
        #pragma unroll
        for (int v = 0; v < 2; ++v) {
            float4 c4 = cg[v*512 + t];
            int fi = (v*512 + t) * 4;
            int r = fi >> 6, cc = fi & 63;
            float* p = cont + r*65 + cc;
            p[0] = c4.x; p[1] = c4.y; p[2] = c4.z; p[3] = c4.w;
        }
    }

    const size_t p3 = ((size_t)b*64 + i)*3;
    const size_t p4 = ((size_t)b*64 + i)*4;
    float bpx=pos[p3],   bpy=pos[p3+1],   bpz=pos[p3+2];
    float bvx=vel[p3],   bvy=vel[p3+1],   bvz=vel[p3+2];
    float brw=rot[p4],   brx=rot[p4+1],   bry=rot[p4+2],  brz=rot[p4+3];
    float box=omega[p3], boy=omega[p3+1], boz=omega[p3+2];
    float m  = mass[(size_t)b*64+i];
    float Ix=inertia[p3], Iy=inertia[p3+1], Iz=inertia[p3+2];
    float Fex=Fext[p3],   Fey=Fext[p3+1],   Fez=Fext[p3+2];
    float tx=tau[p3],     ty=tau[p3+1],     tz=tau[p3+2];
    float dragc = -0.5f * RHO * CD_ * softplus_f(log_A[i]);
    float kc = softplus_f(SLANE(log_k[0]));
    float bc = softplus_f(SLANE(log_b[0]));
    float invm = 1.0f / m;
    float iIx = 1.0f/fmaxf(Ix,1e-6f), iIy = 1.0f/fmaxf(Iy,1e-6f), iIz = 1.0f/fmaxf(Iz,1e-6f);

    float cpx=bpx, cpy=bpy, cpz=bpz;
    float cvx=bvx, cvy=bvy, cvz=bvz;
    float crw=brw, crx=brx, cry=bry, crz=brz;
    float cox=box, coy=boy, coz=boz;

    float apx=0,apy=0,apz=0, avx=0,avy=0,avz=0;
    float arw=0,arx=0,ary=0,arz=0, awx=0,awy=0,awz=0;
    float eacc=0.f;

    const int j0 = q << 3;
    float* ob = out + (size_t)b * 13313;
    __syncthreads();   // contacts staged

    #pragma unroll
    for (int s = 0; s < 4; ++s) {
        float Fcx=0.f, Fcy=0.f, Fcz=0.f;
        #pragma unroll
        for (int jj = 0; jj < 8; ++jj) {
            const int j = j0 + jj;
            float pjx = RL(cpx, j), pjy = RL(cpy, j), pjz = RL(cpz, j);
            float vjx = RL(cvx, j), vjy = RL(cvy, j), vjz = RL(cvz, j);
            float dx = pjx - cpx, dy = pjy - cpy, dz = pjz - cpz;
            float dist = fmaxf(sqrtf(dx*dx + dy*dy + dz*dz), 1e-6f);
            float pen  = fmaxf(1.0f - dist, 0.0f);
            float coef = kc * pen * __builtin_amdgcn_rcpf(dist);
            float cbj  = bc * cont[i*65 + j];
            Fcx += coef*dx + cbj*(vjx - cvx);
            Fcy += coef*dy + cbj*(vjy - cvy);
            Fcz += coef*dz + cbj*(vjz - cvz);
        }
        sF[q*192 + i*3+0] = Fcx;
        sF[q*192 + i*3+1] = Fcy;
        sF[q*192 + i*3+2] = Fcz;
        __syncthreads();
        Fcx = 0.f; Fcy = 0.f; Fcz = 0.f;
        #pragma unroll
        for (int qq = 0; qq < 8; ++qq) {
            Fcx += sF[qq*192 + i*3+0];
            Fcy += sF[qq*192 + i*3+1];
            Fcz += sF[qq*192 + i*3+2];
        }

        float vm = fmaxf(sqrtf(cvx*cvx+cvy*cvy+cvz*cvz), 1e-6f);
        float dc = dragc * vm;
        float Fdx = dc*cvx, Fdy = dc*cvy, Fdz = dc*cvz;

        float dvx = (Fex + Fdx + Fcx) * invm;
        float dvy = (Fey + Fdy + Fcy) * invm;
        float dvz = (Fez - m*G_ACC + Fdz + Fcz) * invm;

        if (s == 0 && q == 0) {   // forces output needs only k1: write now
            ob[832 + i*3+0] = Fex + m*dvx;
            ob[832 + i*3+1] = Fey + m*dvy;
            ob[832 + i*3+2] = Fez + m*dvz;
        }

        float dqw = 0.5f*(-crx*cox - cry*coy - crz*coz);
        float dqx = 0.5f*( crw*cox + cry*coz - crz*coy);
        float dqy = 0.5f*( crw*coy - crx*coz + crz*cox);
        float dqz = 0.5f*( crw*coz + crx*coy - cry*cox);

        float Iox = Ix*cox, Ioy = Iy*coy, Ioz = Iz*coz;
        float dwx = (tx - (coy*Ioz - coz*Ioy)) * iIx;
        float dwy = (ty - (coz*Iox - cox*Ioz)) * iIy;
        float dwz = (tz - (cox*Ioy - coy*Iox)) * iIz;

        float ei = (Fex+Fdx)*cvx + (Fey+Fdy)*cvy + (Fez+Fdz)*cvz;
        #pragma unroll
        for (int off = 32; off > 0; off >>= 1) ei += __shfl_xor(ei, off, 64);

        const float w = (s == 0 || s == 3) ? 1.f : 2.f;
        eacc += w * ei;
        apx += w*cvx; apy += w*cvy; apz += w*cvz;
        avx += w*dvx; avy += w*dvy; avz += w*dvz;
        arw += w*dqw; arx += w*dqx; ary += w*dqy; arz += w*dqz;
        awx += w*dwx; awy += w*dwy; awz += w*dwz;

        if (s < 3) {
            const float h = (s == 2) ? DT : DT*0.5f;
            float npx = bpx + h*cvx, npy = bpy + h*cvy, npz = bpz + h*cvz;
            cvx = bvx + h*dvx; cvy = bvy + h*dvy; cvz = bvz + h*dvz;
            cpx = npx; cpy = npy; cpz = npz;
            float qw = brw + h*dqw, qx = brx + h*dqx, qy = bry + h*dqy, qz = brz + h*dqz;
            float iqn = 1.0f / fmaxf(sqrtf(qw*qw+qx*qx+qy*qy+qz*qz), 1e-12f);
            crw = qw*iqn; crx = qx*iqn; cry = qy*iqn; crz = qz*iqn;
            cox = box + h*dwx; coy = boy + h*dwy; coz = boz + h*dwz;
            __syncthreads();   // WAR: sF reads done before next stage's writes
        }
    }

    if (q == 0) {
        const float s6 = DT / 6.0f;
        ob[      i*3+0] = bpx + s6*apx;  ob[      i*3+1] = bpy + s6*apy;  ob[      i*3+2] = bpz + s6*apz;
        ob[192 + i*3+0] = bvx + s6*avx;  ob[192 + i*3+1] = bvy + s6*avy;  ob[192 + i*3+2] = bvz + s6*avz;
        {
            float qw=brw+s6*arw, qx=brx+s6*arx, qy=bry+s6*ary, qz=brz+s6*arz;
            float iq = 1.0f / fmaxf(sqrtf(qw*qw+qx*qx+qy*qy+qz*qz), 1e-12f);
            ob[384 + i*4+0]=qw*iq; ob[384 + i*4+1]=qx*iq; ob[384 + i*4+2]=qy*iq; ob[384 + i*4+3]=qz*iq;
        }
        ob[640 + i*3+0] = box + s6*awx;  ob[640 + i*3+1] = boy + s6*awy;  ob[640 + i*3+2] = boz + s6*awz;
        if (i == 0) ob[1024] = energy[b] + s6*eacc;
    }
}

extern "C" void kernel_launch(void* const* d_in, const int* in_sizes, int n_in,
                              void* d_out, int out_size, void* d_ws, size_t ws_size,
                              hipStream_t stream) {
    const float* pos      = (const float*)d_in[0];
    const float* vel      = (const float*)d_in[1];
    const float* rot      = (const float*)d_in[2];
    const float* omega    = (const float*)d_in[3];
    const float* mass     = (const float*)d_in[4];
    const float* inertia  = (const float*)d_in[5];
    const float* contacts = (const float*)d_in[6];
    const float* energy   = (const float*)d_in[7];
    const float* fluid_v  = (const float*)d_in[8];
    const float* Fext     = (const float*)d_in[9];
    const float* tau      = (const float*)d_in[10];
    const float* log_A    = (const float*)d_in[11];
    const float* log_k    = (const float*)d_in[12];
    const float* log_b    = (const float*)d_in[13];
    const float* conv_w   = (const float*)d_in[14];
    float* out = (float*)d_out;

    fused_kernel<<<dim3(2048), dim3(512), 0, stream>>>(
        pos, vel, rot, omega, mass, inertia, contacts, energy, fluid_v,
        Fext, tau, log_A, log_k, log_b, conv_w, out);
}